// Round 6
// baseline (298.236 us; speedup 1.0000x reference)
//
#include <hip/hip_runtime.h>
#include <hip/hip_bf16.h>

// Swin window attention: B=16, N=1024 (32x32), NH=8, HD=64, DIM=512
// out: [16, 512, 32, 32] fp32

typedef __attribute__((ext_vector_type(4))) float  f32x4;
typedef __attribute__((ext_vector_type(8))) short  s16x8;
typedef __attribute__((ext_vector_type(4))) short  s16x4;

#define LOG2E 1.44269504f

__device__ __forceinline__ short f2bf(float f) {
    union { float f; unsigned u; } v; v.f = f;
    unsigned r = v.u + 0x7fffu + ((v.u >> 16) & 1u);  // RNE
    return (short)(r >> 16);
}
__device__ __forceinline__ unsigned f2u(float f) {
    union { float f; unsigned u; } v; v.f = f; return v.u;
}
// RNE-pack two f32 -> packed bf16x2 (lo=a, hi=b) via v_perm (verified R2/R3)
__device__ __forceinline__ unsigned pack2(float a, float b) {
    unsigned ua = f2u(a), ub = f2u(b);
    ua += 0x7fffu + ((ua >> 16) & 1u);
    ub += 0x7fffu + ((ub >> 16) & 1u);
    return __builtin_amdgcn_perm(ub, ua, 0x07060302);
}
// 16B LDS ops (strides chosen 16B-aligned -> single b128)
__device__ __forceinline__ s16x8 ld16(const short* p) { return *(const s16x8*)p; }
__device__ __forceinline__ void st16(short* p, s16x8 v) { *(s16x8*)p = v; }
// async global->LDS, 16B per lane, LDS dest = wave-uniform base + lane*16
__device__ __forceinline__ void gld16(const short* g, short* l) {
    __builtin_amdgcn_global_load_lds(
        (const __attribute__((address_space(1))) unsigned int*)g,
        (__attribute__((address_space(3))) unsigned int*)l,
        16, 0, 0);
}

// ---------------- f32 -> bf16 conversion ----------------
__global__ void cvt_kernel(const float* __restrict__ src, short* __restrict__ dst) {
    int i = blockIdx.x * 256 + threadIdx.x;
    f32x4 v = ((const f32x4*)src)[i];
    s16x4 o;
    o[0]=f2bf(v[0]); o[1]=f2bf(v[1]); o[2]=f2bf(v[2]); o[3]=f2bf(v[3]);
    ((s16x4*)dst)[i] = o;
}

// ---------------- bias expand: f32 C-init layout [h][q][it][quad][nf][r], *log2e ----------------
__global__ void bias_expand(const float* __restrict__ table, const int* __restrict__ ridx,
                            float* __restrict__ out) {
    int i = blockIdx.x * 256 + threadIdx.x;        // q*1024 + k
    int n = i >> 10, m = i & 1023;
    int idx = ridx[i];
    const float* t = table + idx * 8;
    int pos = n*1024 + (m >> 7)*128 + ((m >> 2) & 3)*32 + ((m >> 4) & 7)*4 + (m & 3);
    #pragma unroll
    for (int h = 0; h < 8; h++)
        out[h * 1048576 + pos] = t[h] * LOG2E;
}

// ---------------- QKV GEMM (m97-style): Xb[16384,512] x W[1536,512]^T -> q,k,vt bf16 ----------------
__global__ __launch_bounds__(256) void qkv_gemm(
    const short* __restrict__ Xb, const short* __restrict__ W,
    const float* __restrict__ bias,
    short* __restrict__ qb, short* __restrict__ kb, short* __restrict__ vtb)
{
    __shared__ __align__(16) short smem[8192];     // As[128][32] | Bs[128][32], unpadded
    short* As = smem;
    short* Bs = smem + 4096;
    const int tid = threadIdx.x;
    const int lane = tid & 63, w = tid >> 6;
    const int quad = lane >> 4, l16 = lane & 15;
    const int m0 = blockIdx.y * 128, n0 = blockIdx.x * 128;
    const int wm = (w >> 1) * 64, wn = (w & 1) * 64;
    f32x4 acc[4][4] = {};

    // wave w stages rows [w*32, w*32+32) of A and B: 2 calls of 16 rows each
    const int srow = lane >> 2, scol = (lane & 3) * 8;
    const short* ga = Xb + (m0 + w*32 + srow) * 512 + scol;
    const short* gb = W  + (n0 + w*32 + srow) * 512 + scol;
    short* la = As + w * 32 * 32;
    short* lb = Bs + w * 32 * 32;

    for (int k0 = 0; k0 < 512; k0 += 32) {
        __syncthreads();
        gld16(ga + k0,           la);
        gld16(ga + k0 + 16*512,  la + 16*32);
        gld16(gb + k0,           lb);
        gld16(gb + k0 + 16*512,  lb + 16*32);
        asm volatile("s_waitcnt vmcnt(0)" ::: "memory");
        __syncthreads();
        s16x8 af[4], bfr[4];
        #pragma unroll
        for (int i = 0; i < 4; i++) af[i]  = ld16(&As[(wm + i*16 + l16)*32 + quad*8]);
        #pragma unroll
        for (int j = 0; j < 4; j++) bfr[j] = ld16(&Bs[(wn + j*16 + l16)*32 + quad*8]);
        #pragma unroll
        for (int i = 0; i < 4; i++)
            #pragma unroll
            for (int j = 0; j < 4; j++)
                acc[i][j] = __builtin_amdgcn_mfma_f32_16x16x32_bf16(af[i], bfr[j], acc[i][j], 0, 0, 0);
    }

    #pragma unroll
    for (int j = 0; j < 4; j++) {
        int col = n0 + wn + j*16 + l16;
        int which = col >> 9, rem = col & 511, h = rem >> 6, d = rem & 63;
        float bv = bias[col];
        #pragma unroll
        for (int i = 0; i < 4; i++) {
            int row = m0 + wm + i*16 + quad*4;
            int bi = row >> 10, n = row & 1023;
            if (which == 2) {
                uint2 pk;
                pk.x = pack2(acc[i][j][0] + bv, acc[i][j][1] + bv);
                pk.y = pack2(acc[i][j][2] + bv, acc[i][j][3] + bv);
                *(uint2*)&vtb[((bi*8 + h)*64 + d)*1024 + n] = pk;
            } else {
                #pragma unroll
                for (int r = 0; r < 4; r++) {
                    float v = acc[i][j][r] + bv;
                    if (which == 0)
                        qb[((bi*8 + h)*1024 + n + r)*64 + d] = f2bf(v * (0.125f * LOG2E));
                    else
                        kb[((bi*8 + h)*1024 + n + r)*64 + d] = f2bf(v);
                }
            }
        }
    }
}

// ---------------- Flash attention (S^T, ONLINE softmax): 512 thr, Q 128, K-tile 128 ----------------
__global__ __launch_bounds__(512, 4) void attn_kernel(
    const short* __restrict__ qbuf, const short* __restrict__ kbuf,
    const short* __restrict__ vtbuf, const float* __restrict__ bxf,
    short* __restrict__ ao)
{
    // R1 (17408 shorts = 34816 B): Q/K [128][72] (18432 B) / P 8x[16][136] (34816 B)
    // Vs (8704 shorts = 17408 B):  [64][136]
    __shared__ __align__(16) short smem[26112];    // 52224 B -> 3 blocks/CU
    short* R1 = smem;
    short* Vs = smem + 17408;

    const int bh = blockIdx.y;              // 0..127
    const int b = bh >> 3, h = bh & 7;
    const int q0 = blockIdx.x * 128;
    const int tid = threadIdx.x, lane = tid & 63, w = tid >> 6;
    const int quad = lane >> 4, l16 = lane & 15;

    const short* qg = qbuf + (bh*1024 + q0) * 64;
    const short* kg = kbuf + bh * 65536;
    const short* vg = vtbuf + bh * 65536;

    // stage Q (128x64), stride 72
    {
        int r = tid >> 3, c = (tid & 7) * 8;
        #pragma unroll
        for (int p = 0; p < 2; p++)
            st16(&R1[(r + p*64)*72 + c], *(const s16x8*)(qg + (r + p*64)*64 + c));
    }
    __syncthreads();
    s16x8 aq[2];                            // B-frag: n = l16 = wave's q row
    aq[0] = ld16(&R1[(w*16 + l16)*72 + quad*8]);
    aq[1] = ld16(&R1[(w*16 + l16)*72 + 32 + quad*8]);

    float mrow = -1e30f, lrow = 0.f;        // per-lane online state (q = l16)
    f32x4 oacc[4] = {};
    short* Pw = R1 + w * 2176;              // [16 q][136 k] per wave
    const f32x4* bbase = (const f32x4*)bxf + ((((long)q0 + w*16 + l16)*8)*4 + quad)*8;

    for (int it = 0; it < 8; it++) {
        const int k0 = it * 128;
        __syncthreads();                    // B1: prev-iter LDS reads done

        // bias C-init: 8 x 16B f32 loads (this lane's [nf] slice)
        f32x4 s[8];
        {
            const f32x4* bp = bbase + it*32;
            #pragma unroll
            for (int nf = 0; nf < 8; nf++) s[nf] = bp[nf];
        }

        // stage K (128x64 -> stride 72) and V^T (64x128 -> stride 136)
        {
            int r = tid >> 3, c = (tid & 7) * 8;
            #pragma unroll
            for (int p = 0; p < 2; p++)
                st16(&R1[(r + p*64)*72 + c], *(const s16x8*)(kg + (k0 + r + p*64)*64 + c));
        }
        {
            int r = tid >> 4, c = (tid & 15) * 8;
            #pragma unroll
            for (int p = 0; p < 2; p++)
                st16(&Vs[(r + p*32)*136 + c], *(const s16x8*)(vg + (r + p*32)*1024 + k0 + c));
        }
        __syncthreads();                    // B2: staging visible

        // S^T = K Q^T + bias.  s[nf][r]: k = nf*16+quad*4+r, q = l16
        #pragma unroll
        for (int nf = 0; nf < 8; nf++) {
            s16x8 bk0 = ld16(&R1[(nf*16 + l16)*72 + quad*8]);
            s16x8 bk1 = ld16(&R1[(nf*16 + l16)*72 + 32 + quad*8]);
            s[nf] = __builtin_amdgcn_mfma_f32_16x16x32_bf16(bk0, aq[0], s[nf], 0, 0, 0);
            s[nf] = __builtin_amdgcn_mfma_f32_16x16x32_bf16(bk1, aq[1], s[nf], 0, 0, 0);
        }

        // online softmax over k: 32 in-lane values + 2 cross-quad shuffles
        float mx = s[0][0];
        #pragma unroll
        for (int nf = 0; nf < 8; nf++) {
            float a = fmaxf(s[nf][0], s[nf][1]), c = fmaxf(s[nf][2], s[nf][3]);
            mx = fmaxf(mx, fmaxf(a, c));
        }
        mx = fmaxf(mx, __shfl_xor(mx, 16));
        mx = fmaxf(mx, __shfl_xor(mx, 32));
        float mnew = fmaxf(mrow, mx);
        float alpha = __builtin_exp2f(mrow - mnew);
        mrow = mnew;
        float rs = 0.f;
        #pragma unroll
        for (int nf = 0; nf < 8; nf++)
            #pragma unroll
            for (int r = 0; r < 4; r++) {
                float p = __builtin_exp2f(s[nf][r] - mnew);
                s[nf][r] = p;
                rs += p;
            }
        rs += __shfl_xor(rs, 16);
        rs += __shfl_xor(rs, 32);
        lrow = lrow * alpha + rs;

        // pack P (RNE) before the barrier so VALU overlaps barrier wait
        uint2 pk[8];
        #pragma unroll
        for (int nf = 0; nf < 8; nf++) {
            pk[nf].x = pack2(s[nf][0], s[nf][1]);
            pk[nf].y = pack2(s[nf][2], s[nf][3]);
        }

        // rescale O: alpha for q_local = quad*4 + r (broadcast from lanes 0..15)
        float a_r[4];
        #pragma unroll
        for (int r = 0; r < 4; r++) a_r[r] = __shfl(alpha, quad*4 + r);
        #pragma unroll
        for (int df = 0; df < 4; df++)
            #pragma unroll
            for (int r = 0; r < 4; r++)
                oacc[df][r] *= a_r[r];

        __syncthreads();                    // B3: all waves done with Ks; P may overwrite

        // P store: per nf one b64 (4 k-contiguous bf16 at row q=l16)
        #pragma unroll
        for (int nf = 0; nf < 8; nf++)
            *(uint2*)&Pw[l16*136 + nf*16 + quad*4] = pk[nf];
        asm volatile("s_waitcnt lgkmcnt(0)" ::: "memory");  // wave-local visibility

        // O += P @ V   (A = P[q][k], B = V^T[d][k])
        #pragma unroll
        for (int ks = 0; ks < 4; ks++) {
            s16x8 ap = ld16(&Pw[l16*136 + ks*32 + quad*8]);
            #pragma unroll
            for (int df = 0; df < 4; df++) {
                s16x8 bv = ld16(&Vs[(df*16 + l16)*136 + ks*32 + quad*8]);
                oacc[df] = __builtin_amdgcn_mfma_f32_16x16x32_bf16(ap, bv, oacc[df], 0, 0, 0);
            }
        }
    }

    // epilogue: O row = q_local quad*4+r, col d = df*16+l16
    float inv_r[4];
    #pragma unroll
    for (int r = 0; r < 4; r++) inv_r[r] = 1.0f / __shfl(lrow, quad*4 + r);
    #pragma unroll
    for (int r = 0; r < 4; r++) {
        int n = q0 + w*16 + quad*4 + r;
        #pragma unroll
        for (int df = 0; df < 4; df++)
            ao[(b*1024 + n)*512 + h*64 + df*16 + l16] = f2bf(oacc[df][r] * inv_r[r]);
    }
}

// ---------------- Proj GEMM (m97-style) + coalesced transposed epilogue ----------------
__global__ __launch_bounds__(256) void proj_gemm(
    const short* __restrict__ A, const short* __restrict__ W,
    const float* __restrict__ bias, float* __restrict__ out)
{
    __shared__ __align__(16) short smemp[9216];    // As[128][32] | Bs[128][32]; Ts needs 16896B
    short* As = smemp;
    short* Bs = smemp + 4096;
    const int tid = threadIdx.x;
    const int lane = tid & 63, w = tid >> 6;
    const int quad = lane >> 4, l16 = lane & 15;
    const int m0 = blockIdx.y * 128, n0 = blockIdx.x * 128;
    const int wm = (w >> 1) * 64, wn = (w & 1) * 64;
    f32x4 acc[4][4] = {};

    const int srow = lane >> 2, scol = (lane & 3) * 8;
    const short* ga = A + (m0 + w*32 + srow) * 512 + scol;
    const short* gb = W + (n0 + w*32 + srow) * 512 + scol;
    short* la = As + w * 32 * 32;
    short* lb = Bs + w * 32 * 32;

    for (int k0 = 0; k0 < 512; k0 += 32) {
        __syncthreads();
        gld16(ga + k0,           la);
        gld16(ga + k0 + 16*512,  la + 16*32);
        gld16(gb + k0,           lb);
        gld16(gb + k0 + 16*512,  lb + 16*32);
        asm volatile("s_waitcnt vmcnt(0)" ::: "memory");
        __syncthreads();
        s16x8 af[4], bfr[4];
        #pragma unroll
        for (int i = 0; i < 4; i++) af[i]  = ld16(&As[(wm + i*16 + l16)*32 + quad*8]);
        #pragma unroll
        for (int j = 0; j < 4; j++) bfr[j] = ld16(&Bs[(wn + j*16 + l16)*32 + quad*8]);
        #pragma unroll
        for (int i = 0; i < 4; i++)
            #pragma unroll
            for (int j = 0; j < 4; j++)
                acc[i][j] = __builtin_amdgcn_mfma_f32_16x16x32_bf16(af[i], bfr[j], acc[i][j], 0, 0, 0);
    }

    // epilogue: LDS transpose -> coalesced out[b][c][n] writes
    const int bi = m0 >> 10, nbase = m0 & 1023;
    float* Ts = (float*)smemp;              // [32][132] f32 = 16896 B <= 18432 B
    #pragma unroll
    for (int ci = 0; ci < 4; ci++) {
        __syncthreads();
        if ((w & 1) == (ci >> 1)) {
            #pragma unroll
            for (int jj = 0; jj < 2; jj++) {
                int j = (ci & 1) * 2 + jj;
                int c = n0 + wn + j*16 + l16;
                float bv = bias[c];
                int cl = jj*16 + l16;
                #pragma unroll
                for (int i = 0; i < 4; i++) {
                    f32x4 v = acc[i][j];
                    v[0] += bv; v[1] += bv; v[2] += bv; v[3] += bv;
                    *(f32x4*)&Ts[cl*132 + wm + i*16 + quad*4] = v;
                }
            }
        }
        __syncthreads();
        #pragma unroll
        for (int p = 0; p < 4; p++) {
            int row = (tid >> 5) + p*8, col = (tid & 31)*4;
            f32x4 v = *(const f32x4*)&Ts[row*132 + col];
            *(f32x4*)&out[(bi*512 + n0 + ci*32 + row)*1024 + nbase + col] = v;
        }
    }
}

extern "C" void kernel_launch(void* const* d_in, const int* in_sizes, int n_in,
                              void* d_out, int out_size, void* d_ws, size_t ws_size,
                              hipStream_t stream) {
    const float* x      = (const float*)d_in[0];   // [16,1024,512]
    const float* qkv_w  = (const float*)d_in[1];   // [1536,512]
    const float* qkv_b  = (const float*)d_in[2];   // [1536]
    const float* proj_w = (const float*)d_in[3];   // [512,512]
    const float* proj_b = (const float*)d_in[4];   // [512]
    const float* btab   = (const float*)d_in[5];   // [3969,8]
    const int*   ridx   = (const int*)d_in[6];     // [1024,1024]
    float* out = (float*)d_out;

    short* ws    = (short*)d_ws;
    short* wqkv  = ws;                          // 1536*512
    short* wproj = wqkv + 1536*512;             // 512*512
    short* qb    = wproj + 512*512;             // 16*8*1024*64
    short* kb    = qb  + 16*8*1024*64;
    short* vtb   = kb  + 16*8*1024*64;
    float* bxf   = (float*)(vtb + 16*8*1024*64);  // 8*1024*1024 f32 (C-init layout, *log2e)
    short* ao    = (short*)(bxf + 8*1024*1024); // 16384*512 bf16; aliased as xb pre-attn
    short* xb    = ao;

    cvt_kernel<<<8192, 256, 0, stream>>>(x, xb);          // X f32 -> bf16
    cvt_kernel<<<768, 256, 0, stream>>>(qkv_w, wqkv);
    cvt_kernel<<<256, 256, 0, stream>>>(proj_w, wproj);
    bias_expand<<<4096, 256, 0, stream>>>(btab, ridx, bxf);
    qkv_gemm<<<dim3(12, 128), 256, 0, stream>>>(xb, wqkv, qkv_b, qb, kb, vtb);
    attn_kernel<<<dim3(8, 128), 512, 0, stream>>>(qb, kb, vtb, bxf, ao);
    proj_gemm<<<dim3(4, 128), 256, 0, stream>>>(ao, wproj, proj_b, out);
}